// Round 6
// baseline (145.393 us; speedup 1.0000x reference)
//
#include <hip/hip_runtime.h>

#define LOG2E 1.4426950408889634f
#define POISON 0xAAAAAAAAu

typedef __bf16 bf16x8 __attribute__((ext_vector_type(8)));
typedef float  f32x4  __attribute__((ext_vector_type(4)));

#define TSTR 76            // GEMM LDS tile row stride (shorts): 152 B -> <=2-way b128 reads
#define LSTR 20            // pair LDS row stride (floats): 80 B, 16B-aligned

__device__ inline unsigned short f2bf(float f){
  unsigned u = __float_as_uint(f);
  unsigned r = u + 0x7FFFu + ((u >> 16) & 1u);   // RNE; inputs finite
  return (unsigned short)(r >> 16);
}
__device__ inline unsigned pack2(float lo, float hi){
  return (unsigned)f2bf(lo) | ((unsigned)f2bf(hi) << 16);
}

// ONE kernel, grid 256 x 1024 thr (16 waves), co-resident (<=2 blocks/CU capacity).
// Phase 1: K-split GEMM  P[ks][256][1024] = x[:,ks*256:+256] @ W[ks*256:+256,:]
// Barrier: SINGLE arrival counter in d_ws. Counter starts at harness poison
//   0xAAAAAAAA (documented, re-poisoned before EVERY launch); each block does one
//   relaxed agent fetch_add(+1); ONE thread per block polls ONE dword with
//   s_sleep backoff (256 loads/round chip-wide vs 65536 in R5 -> no TCC storm).
// Phase 2: pair, identical math to R5.
__global__ __launch_bounds__(1024) void k_fused(const float* __restrict__ X,
                                                const float* __restrict__ Wm,
                                                const float* __restrict__ bias,
                                                float* __restrict__ P,
                                                unsigned* __restrict__ count,
                                                float* __restrict__ out){
  __shared__ union {
    struct { unsigned short As[64 * TSTR]; unsigned short Bs[64 * TSTR]; } g;
    struct { float L[256 * LSTR]; float red[16][64]; } p;
  } sm;

  const int bx = blockIdx.x;
  const int t = threadIdx.x;
  const int lane = t & 63, w = t >> 6;          // 16 waves
  const int r16 = lane & 15, quad = lane >> 4;

  // ---------------- Phase 1: GEMM ----------------
  {
    const int m0 = (bx & 3) * 64;
    const int n0 = ((bx >> 2) & 15) * 64;
    const int k0 = (bx >> 6) * 256;

    const int arow = t >> 4, akq = t & 15;      // A: row, 4-float k-chunk
    const int bn = t & 63, bkq = t >> 6;        // B: n-col, 4-krow chunk
    const float* ap = X + (size_t)(m0 + arow) * 1024 + k0 + akq * 4;
    const float* bp = Wm + (size_t)(k0 + bkq * 4) * 1024 + n0 + bn;

    const int mw = w & 3, nw = w >> 2;          // wave's 16x16 tile
    f32x4 acc = {0.f, 0.f, 0.f, 0.f};

    float4 pa = *(const float4*)ap;
    float pb0 = bp[0], pb1 = bp[1024], pb2 = bp[2048], pb3 = bp[3072];

    #pragma unroll
    for (int kt = 0; kt < 256; kt += 64){
      __syncthreads();                          // prev iter ds_reads done
      { // A: 4 floats -> 4 bf16, 8B store
        uint2 ua; ua.x = pack2(pa.x, pa.y); ua.y = pack2(pa.z, pa.w);
        *(uint2*)(&sm.g.As[arow * TSTR + akq * 4]) = ua;
      }
      { // B: 4 k-adjacent floats -> 4 bf16 at [n][k]
        uint2 ub; ub.x = pack2(pb0, pb1); ub.y = pack2(pb2, pb3);
        *(uint2*)(&sm.g.Bs[bn * TSTR + bkq * 4]) = ub;
      }
      __syncthreads();
      if (kt < 192){                            // prefetch next k-tile
        pa = *(const float4*)(ap + kt + 64);
        const float* nb_ = bp + (size_t)(kt + 64) * 1024;
        pb0 = nb_[0]; pb1 = nb_[1024]; pb2 = nb_[2048]; pb3 = nb_[3072];
      }
      #pragma unroll
      for (int kk = 0; kk < 2; ++kk){
        const int ko = kk * 32 + quad * 8;
        bf16x8 a = *(const bf16x8*)(&sm.g.As[(mw * 16 + r16) * TSTR + ko]);
        bf16x8 b = *(const bf16x8*)(&sm.g.Bs[(nw * 16 + r16) * TSTR + ko]);
        acc = __builtin_amdgcn_mfma_f32_16x16x32_bf16(a, b, acc, 0, 0, 0);
      }
    }
    // C/D layout (verified): col = lane&15, row = (lane>>4)*4 + reg
    float* Pz = P + (size_t)(bx >> 6) * 256 * 1024;
    #pragma unroll
    for (int r = 0; r < 4; ++r){
      const int row = m0 + mw * 16 + quad * 4 + r;
      const int col = n0 + nw * 16 + r16;
      Pz[(size_t)row * 1024 + col] = acc[r];
    }
  }

  // ---------------- Grid barrier (single counter) ----------------
  __syncthreads();
  if (t == 0){
    __threadfence();                            // release P stores
    __hip_atomic_fetch_add(count, 1u, __ATOMIC_RELAXED, __HIP_MEMORY_SCOPE_AGENT);
    const unsigned target = POISON + 256u;      // counter starts at harness poison
    while (__hip_atomic_load(count, __ATOMIC_RELAXED, __HIP_MEMORY_SCOPE_AGENT) != target)
      __builtin_amdgcn_s_sleep(8);              // ~512 cyc backoff
  }
  __syncthreads();
  __threadfence();                              // acquire side for P reads

  // ---------------- Phase 2: pair ----------------
  {
    const int b = bx >> 2, jc = bx & 3;

    { // stage + reduce the 4 K-split partials: thread -> one float4 of L
      const int i = t >> 2, q = t & 3;
      const float* base = P + (size_t)i * 1024 + b * 16 + q * 4;
      float4 s0 = *(const float4*)(base);
      float4 s1 = *(const float4*)(base + 256 * 1024);
      float4 s2 = *(const float4*)(base + 512 * 1024);
      float4 s3 = *(const float4*)(base + 768 * 1024);
      float4 r;
      r.x = (s0.x + s1.x) + (s2.x + s3.x);
      r.y = (s0.y + s1.y) + (s2.y + s3.y);
      r.z = (s0.z + s1.z) + (s2.z + s3.z);
      r.w = (s0.w + s1.w) + (s2.w + s3.w);
      *(float4*)(&sm.p.L[i * LSTR + q * 4]) = r;
    }
    __syncthreads();

    const int j = jc * 64 + lane;
    float oj[16];
    #pragma unroll
    for (int q = 0; q < 4; ++q){
      float4 v = *(const float4*)(&sm.p.L[j * LSTR + q * 4]);
      oj[q*4+0] = v.x; oj[q*4+1] = v.y; oj[q*4+2] = v.z; oj[q*4+3] = v.w;
    }

    float acc = 0.f;
    const int i0 = w * 16;
    #pragma unroll 4
    for (int ii = i0; ii < i0 + 16; ++ii){
      const float4* fr = (const float4*)(&sm.p.L[ii * LSTR]);  // wave-uniform -> broadcast
      float4 f0 = fr[0], f1 = fr[1], f2 = fr[2], f3 = fr[3];
      float p0 = fabsf(oj[0]  - f0.x) + fabsf(oj[1]  - f0.y)
               + fabsf(oj[2]  - f0.z) + fabsf(oj[3]  - f0.w);
      float p1 = fabsf(oj[4]  - f1.x) + fabsf(oj[5]  - f1.y)
               + fabsf(oj[6]  - f1.z) + fabsf(oj[7]  - f1.w);
      float p2 = fabsf(oj[8]  - f2.x) + fabsf(oj[9]  - f2.y)
               + fabsf(oj[10] - f2.z) + fabsf(oj[11] - f2.w);
      float p3 = fabsf(oj[12] - f3.x) + fabsf(oj[13] - f3.y)
               + fabsf(oj[14] - f3.z) + fabsf(oj[15] - f3.w);
      acc += exp2f(-LOG2E * ((p0 + p1) + (p2 + p3)));
    }
    sm.p.red[w][lane] = acc;
    __syncthreads();
    if (w == 0){
      float tot = 0.f;
      #pragma unroll
      for (int ww = 0; ww < 16; ++ww) tot += sm.p.red[ww][lane];
      out[(size_t)j * 64 + b] = tot + bias[b];
    }
  }
}

extern "C" void kernel_launch(void* const* d_in, const int* in_sizes, int n_in,
                              void* d_out, int out_size, void* d_ws, size_t ws_size,
                              hipStream_t stream){
  const float* x    = (const float*)d_in[0];   // [256][1024]
  const float* W    = (const float*)d_in[1];   // [1024][1024] k-major
  const float* bias = (const float*)d_in[2];   // [64]
  float* out = (float*)d_out;                  // [256][64]
  float* P   = (float*)d_ws;                   // 4 MB: partials [4][256][1024]
  unsigned* count = (unsigned*)(P + 4 * 256 * 1024);  // arrival counter (poisoned 0xAA..)

  k_fused<<<256, 1024, 0, stream>>>(x, W, bias, P, count, out);
}

// Round 7
// 102.577 us; speedup vs baseline: 1.4174x; 1.4174x over previous
//
#include <hip/hip_runtime.h>

#define LOG2E 1.4426950408889634f

typedef __bf16 bf16x8 __attribute__((ext_vector_type(8)));
typedef float  f32x4  __attribute__((ext_vector_type(4)));

#define WSTR 1032   // Wb row stride (bf16): 2064 B = 516 dw == 4 mod 32 banks -> 2-way (free) on b128
#define LSTR 20     // L row stride (floats): 80 B

__device__ inline unsigned short f2bf(float f){            // RNE (W staging, one-time)
  unsigned u = __float_as_uint(f);
  unsigned r = u + 0x7FFFu + ((u >> 16) & 1u);
  return (unsigned short)(r >> 16);
}
// round-half-up pack of two f32 -> two bf16 (3 VALU: add, add, perm)
__device__ inline unsigned pack2r(float lo, float hi){
  unsigned a = __float_as_uint(lo) + 0x8000u;
  unsigned b = __float_as_uint(hi) + 0x8000u;
  return __builtin_amdgcn_perm(b, a, 0x07060302u);         // [b.hi16 : a.hi16]
}

// ONE dispatch, NO inter-block communication, NO workspace.
// grid 256 = (b in [0,64)) x (jc in [0,4)); 1024 thr = 16 waves.
// Phase A: mat_b[256][16] = x @ W[:, b*16:+16]  (each block redundantly; 512 MFMA)
//   - W-slice staged once to LDS Wb[16][1024] bf16 (n-major)
//   - A-frags read straight from global x (f32, L2-resident), packed to bf16 in regs
//   - wave w owns m-tile rows [w*16, +16); D written to LDS L
// Phase B: out[j][b] = bias[b] + sum_i exp(-L1(i,j)), j = jc*64 + lane.
//   i-rows live in registers (4 floats/lane), broadcast via v_readlane (VALU pipe,
//   LDS pipe stays idle) -- i-split across the 16 waves, LDS cross-wave reduce.
__global__ __launch_bounds__(1024) void k_onepass(const float* __restrict__ X,
                                                  const float* __restrict__ Wm,
                                                  const float* __restrict__ bias,
                                                  float* __restrict__ out){
  __shared__ unsigned short Wb[16 * WSTR];   // 33.0 KB
  __shared__ float L[256 * LSTR];            // 20.5 KB
  __shared__ float red[16][64];              //  4.0 KB

  const int bx = blockIdx.x;
  const int b  = bx >> 2, jc = bx & 3;
  const int t  = threadIdx.x;
  const int lane = t & 63, w = t >> 6;       // 16 waves
  const int r16 = lane & 15, quad = lane >> 4;

  // ---- stage W[:, b*16:+16) -> Wb[c][k] bf16 (thread t = k-row t) ----
  {
    const float4* wr = (const float4*)(Wm + (size_t)t * 1024 + b * 16);
    float4 w0 = wr[0], w1 = wr[1], w2 = wr[2], w3 = wr[3];
    unsigned short* d = &Wb[t];
    d[ 0*WSTR] = f2bf(w0.x); d[ 1*WSTR] = f2bf(w0.y); d[ 2*WSTR] = f2bf(w0.z); d[ 3*WSTR] = f2bf(w0.w);
    d[ 4*WSTR] = f2bf(w1.x); d[ 5*WSTR] = f2bf(w1.y); d[ 6*WSTR] = f2bf(w1.z); d[ 7*WSTR] = f2bf(w1.w);
    d[ 8*WSTR] = f2bf(w2.x); d[ 9*WSTR] = f2bf(w2.y); d[10*WSTR] = f2bf(w2.z); d[11*WSTR] = f2bf(w2.w);
    d[12*WSTR] = f2bf(w3.x); d[13*WSTR] = f2bf(w3.y); d[14*WSTR] = f2bf(w3.z); d[15*WSTR] = f2bf(w3.w);
  }
  __syncthreads();

  // ---- Phase A: GEMM, wave w -> rows [w*16, +16) ----
  {
    f32x4 acc = {0.f, 0.f, 0.f, 0.f};
    const float* xrow = X + (size_t)(w * 16 + r16) * 1024 + quad * 8;
    const unsigned short* wrow = &Wb[r16 * WSTR + quad * 8];
    #pragma unroll 4
    for (int ks = 0; ks < 32; ++ks){
      float4 a0 = *(const float4*)(xrow + ks * 32);
      float4 a1 = *(const float4*)(xrow + ks * 32 + 4);
      union { uint4 u; bf16x8 v; } A;
      A.u.x = pack2r(a0.x, a0.y); A.u.y = pack2r(a0.z, a0.w);
      A.u.z = pack2r(a1.x, a1.y); A.u.w = pack2r(a1.z, a1.w);
      bf16x8 B = *(const bf16x8*)(wrow + ks * 32);
      acc = __builtin_amdgcn_mfma_f32_16x16x32_bf16(A.v, B, acc, 0, 0, 0);
    }
    // D layout (verified): col = lane&15, row = quad*4 + reg
    #pragma unroll
    for (int r = 0; r < 4; ++r)
      L[(w * 16 + quad * 4 + r) * LSTR + r16] = acc[r];
  }
  __syncthreads();

  // ---- Phase B: pairwise L1 + exp ----
  {
    // own j-row (pre-scaled by log2 e)
    const int j = jc * 64 + lane;
    float oj[16];
    #pragma unroll
    for (int q = 0; q < 4; ++q){
      float4 v = *(const float4*)(&L[j * LSTR + q * 4]);
      oj[q*4+0] = v.x * LOG2E; oj[q*4+1] = v.y * LOG2E;
      oj[q*4+2] = v.z * LOG2E; oj[q*4+3] = v.w * LOG2E;
    }
    // wave's i-rows in registers: lane = il*4 + q holds c-chunk q of row w*16+il
    float4 vi = *(const float4*)(&L[(w * 16 + (lane >> 2)) * LSTR + (lane & 3) * 4]);
    const int i0 = __float_as_int(vi.x * LOG2E);
    const int i1 = __float_as_int(vi.y * LOG2E);
    const int i2 = __float_as_int(vi.z * LOG2E);
    const int i3 = __float_as_int(vi.w * LOG2E);

    float accs = 0.f;
    #pragma unroll 4
    for (int ii = 0; ii < 16; ++ii){
      const int sl = ii * 4;
      float p0 = fabsf(oj[0]  - __int_as_float(__builtin_amdgcn_readlane(i0, sl)))
               + fabsf(oj[1]  - __int_as_float(__builtin_amdgcn_readlane(i1, sl)))
               + fabsf(oj[2]  - __int_as_float(__builtin_amdgcn_readlane(i2, sl)))
               + fabsf(oj[3]  - __int_as_float(__builtin_amdgcn_readlane(i3, sl)));
      float p1 = fabsf(oj[4]  - __int_as_float(__builtin_amdgcn_readlane(i0, sl + 1)))
               + fabsf(oj[5]  - __int_as_float(__builtin_amdgcn_readlane(i1, sl + 1)))
               + fabsf(oj[6]  - __int_as_float(__builtin_amdgcn_readlane(i2, sl + 1)))
               + fabsf(oj[7]  - __int_as_float(__builtin_amdgcn_readlane(i3, sl + 1)));
      float p2 = fabsf(oj[8]  - __int_as_float(__builtin_amdgcn_readlane(i0, sl + 2)))
               + fabsf(oj[9]  - __int_as_float(__builtin_amdgcn_readlane(i1, sl + 2)))
               + fabsf(oj[10] - __int_as_float(__builtin_amdgcn_readlane(i2, sl + 2)))
               + fabsf(oj[11] - __int_as_float(__builtin_amdgcn_readlane(i3, sl + 2)));
      float p3 = fabsf(oj[12] - __int_as_float(__builtin_amdgcn_readlane(i0, sl + 3)))
               + fabsf(oj[13] - __int_as_float(__builtin_amdgcn_readlane(i1, sl + 3)))
               + fabsf(oj[14] - __int_as_float(__builtin_amdgcn_readlane(i2, sl + 3)))
               + fabsf(oj[15] - __int_as_float(__builtin_amdgcn_readlane(i3, sl + 3)));
      accs += exp2f(-((p0 + p1) + (p2 + p3)));
    }
    red[w][lane] = accs;
    __syncthreads();
    if (w == 0){
      float tot = 0.f;
      #pragma unroll
      for (int ww = 0; ww < 16; ++ww) tot += red[ww][lane];
      out[(size_t)j * 64 + b] = tot + bias[b];
    }
  }
}

extern "C" void kernel_launch(void* const* d_in, const int* in_sizes, int n_in,
                              void* d_out, int out_size, void* d_ws, size_t ws_size,
                              hipStream_t stream){
  const float* x    = (const float*)d_in[0];   // [256][1024]
  const float* W    = (const float*)d_in[1];   // [1024][1024] k-major
  const float* bias = (const float*)d_in[2];   // [64]
  float* out = (float*)d_out;                  // [256][64]
  (void)d_ws; (void)ws_size;

  k_onepass<<<256, 1024, 0, stream>>>(x, W, bias, out);
}

// Round 8
// 84.096 us; speedup vs baseline: 1.7289x; 1.2198x over previous
//
#include <hip/hip_runtime.h>

#define LOG2E 1.4426950408889634f

typedef __bf16 bf16x8 __attribute__((ext_vector_type(8)));
typedef float  f32x4  __attribute__((ext_vector_type(4)));

#define TSTR 76            // GEMM LDS tile row stride (shorts)
#define LSTR 20            // pair LDS row stride (floats)

__device__ inline unsigned short f2bf(float f){
  unsigned u = __float_as_uint(f);
  unsigned r = u + 0x7FFFu + ((u >> 16) & 1u);   // RNE; inputs finite
  return (unsigned short)(r >> 16);
}
__device__ inline unsigned pack2(float lo, float hi){
  return (unsigned)f2bf(lo) | ((unsigned)f2bf(hi) << 16);
}

// ---- K1: K-split GEMM, P[ks][256][1024] = x[:,ks*128:+128] @ W[ks*128:+128,:]
// grid (4 m, 16 n, 8 ks) = 512 blocks -> 2 blocks/CU (cross-block latency overlap),
// 256 thr. f32->bf16 convert + W transpose fused into staging; reg prefetch.
__global__ __launch_bounds__(256) void k_gemm_ks(const float* __restrict__ X,
                                                 const float* __restrict__ Wm,
                                                 float* __restrict__ P){
  __shared__ unsigned short As[64 * TSTR];
  __shared__ unsigned short Bs[64 * TSTR];
  const int m0 = blockIdx.x * 64, n0 = blockIdx.y * 64;
  const int k0 = blockIdx.z * 128;
  const int t = threadIdx.x;
  const int lane = t & 63, w = t >> 6;
  const int wrow = (w & 1) * 32, wcol = (w >> 1) * 32;
  const int r16 = lane & 15, quad = lane >> 4;

  const int ar = t >> 2, aq = t & 3;          // A: row 0..63, 16-float chunk
  const int bc = t & 15, bg = t >> 4;         // B: 4-col group, 4-krow group
  const float* ap = X + (size_t)(m0 + ar) * 1024 + k0 + aq * 16;
  const float* bp = Wm + (size_t)k0 * 1024 + n0 + bc * 4;

  f32x4 acc[2][2];
  #pragma unroll
  for (int p = 0; p < 2; ++p)
    #pragma unroll
    for (int q = 0; q < 2; ++q)
      #pragma unroll
      for (int e = 0; e < 4; ++e) acc[p][q][e] = 0.f;

  float4 pa[4], pb[4];
  #pragma unroll
  for (int r = 0; r < 4; ++r) pa[r] = *(const float4*)(ap + r * 4);
  #pragma unroll
  for (int r = 0; r < 4; ++r) pb[r] = *(const float4*)(bp + (size_t)(4 * bg + r) * 1024);

  #pragma unroll
  for (int kt = 0; kt < 128; kt += 64){
    __syncthreads();                          // prev iter ds_reads done
    { // A tile: 16 floats -> 16 bf16
      unsigned short* d = &As[ar * TSTR + aq * 16];
      uint4 o;
      o.x = pack2(pa[0].x, pa[0].y); o.y = pack2(pa[0].z, pa[0].w);
      o.z = pack2(pa[1].x, pa[1].y); o.w = pack2(pa[1].z, pa[1].w);
      *(uint4*)d = o;
      o.x = pack2(pa[2].x, pa[2].y); o.y = pack2(pa[2].z, pa[2].w);
      o.z = pack2(pa[3].x, pa[3].y); o.w = pack2(pa[3].z, pa[3].w);
      *(uint4*)(d + 8) = o;
    }
    { // B tile: transpose 4 k-rows x 4 n-cols into [n][k]
      #pragma unroll
      for (int e = 0; e < 4; ++e){
        const int n = bc * 4 + e;
        uint2 o;
        o.x = pack2(((const float*)&pb[0])[e], ((const float*)&pb[1])[e]);
        o.y = pack2(((const float*)&pb[2])[e], ((const float*)&pb[3])[e]);
        *(uint2*)(&Bs[n * TSTR + bg * 4]) = o;
      }
    }
    __syncthreads();
    if (kt < 64){                             // prefetch 2nd k-tile
      #pragma unroll
      for (int r = 0; r < 4; ++r) pa[r] = *(const float4*)(ap + 64 + r * 4);
      #pragma unroll
      for (int r = 0; r < 4; ++r) pb[r] = *(const float4*)(bp + (size_t)(64 + 4 * bg + r) * 1024);
    }
    #pragma unroll
    for (int kk = 0; kk < 2; ++kk){
      const int ko = kk * 32 + quad * 8;
      bf16x8 a0 = *(const bf16x8*)(&As[(wrow      + r16) * TSTR + ko]);
      bf16x8 a1 = *(const bf16x8*)(&As[(wrow + 16 + r16) * TSTR + ko]);
      bf16x8 b0 = *(const bf16x8*)(&Bs[(wcol      + r16) * TSTR + ko]);
      bf16x8 b1 = *(const bf16x8*)(&Bs[(wcol + 16 + r16) * TSTR + ko]);
      acc[0][0] = __builtin_amdgcn_mfma_f32_16x16x32_bf16(a0, b0, acc[0][0], 0, 0, 0);
      acc[0][1] = __builtin_amdgcn_mfma_f32_16x16x32_bf16(a0, b1, acc[0][1], 0, 0, 0);
      acc[1][0] = __builtin_amdgcn_mfma_f32_16x16x32_bf16(a1, b0, acc[1][0], 0, 0, 0);
      acc[1][1] = __builtin_amdgcn_mfma_f32_16x16x32_bf16(a1, b1, acc[1][1], 0, 0, 0);
    }
  }
  // C/D layout (verified): col = lane&15, row = (lane>>4)*4 + reg
  float* Pz = P + (size_t)blockIdx.z * 256 * 1024;
  #pragma unroll
  for (int p = 0; p < 2; ++p)
    #pragma unroll
    for (int q = 0; q < 2; ++q)
      #pragma unroll
      for (int r = 0; r < 4; ++r){
        const int row = m0 + wrow + p * 16 + quad * 4 + r;
        const int col = n0 + wcol + q * 16 + r16;
        Pz[(size_t)row * 1024 + col] = acc[p][q][r];
      }
}

// ---- K2: out[j][b] = bias[b] + sum_i exp(-sum_c |mat[i,b,c]-mat[j,b,c]|)
// grid 256 = 64 b x 4 jc; 1024 thr = 16 waves. Staging sums 8 K-split partials
// (8 float4 loads/thread, deep MLP). Pair inner loop: i-rows in registers,
// v_readlane broadcast (VALU pipe only; 2.56 us/CU model), wave w owns 16 i.
__global__ __launch_bounds__(1024) void k_pair(const float* __restrict__ P,
                                               const float* __restrict__ bias,
                                               float* __restrict__ out){
  __shared__ float L[256 * LSTR];
  __shared__ float red[16][64];
  const int b = blockIdx.x >> 2, jc = blockIdx.x & 3;
  const int t = threadIdx.x, lane = t & 63, w = t >> 6;

  { // stage + reduce the 8 K-split partials: thread -> one float4 of L
    const int i = t >> 2, q = t & 3;
    const float* base = P + (size_t)i * 1024 + b * 16 + q * 4;
    float4 s0 = *(const float4*)(base);
    float4 s1 = *(const float4*)(base + 1 * 262144);
    float4 s2 = *(const float4*)(base + 2 * 262144);
    float4 s3 = *(const float4*)(base + 3 * 262144);
    float4 s4 = *(const float4*)(base + 4 * 262144);
    float4 s5 = *(const float4*)(base + 5 * 262144);
    float4 s6 = *(const float4*)(base + 6 * 262144);
    float4 s7 = *(const float4*)(base + 7 * 262144);
    float4 r;
    r.x = ((s0.x + s1.x) + (s2.x + s3.x)) + ((s4.x + s5.x) + (s6.x + s7.x));
    r.y = ((s0.y + s1.y) + (s2.y + s3.y)) + ((s4.y + s5.y) + (s6.y + s7.y));
    r.z = ((s0.z + s1.z) + (s2.z + s3.z)) + ((s4.z + s5.z) + (s6.z + s7.z));
    r.w = ((s0.w + s1.w) + (s2.w + s3.w)) + ((s4.w + s5.w) + (s6.w + s7.w));
    *(float4*)(&L[i * LSTR + q * 4]) = r;
  }
  __syncthreads();

  // own j-row (pre-scaled by log2 e)
  const int j = jc * 64 + lane;
  float oj[16];
  #pragma unroll
  for (int q = 0; q < 4; ++q){
    float4 v = *(const float4*)(&L[j * LSTR + q * 4]);
    oj[q*4+0] = v.x * LOG2E; oj[q*4+1] = v.y * LOG2E;
    oj[q*4+2] = v.z * LOG2E; oj[q*4+3] = v.w * LOG2E;
  }
  // wave's 16 i-rows in registers: lane = il*4 + q holds c-chunk q of row w*16+il
  float4 vi = *(const float4*)(&L[(w * 16 + (lane >> 2)) * LSTR + (lane & 3) * 4]);
  const int i0 = __float_as_int(vi.x * LOG2E);
  const int i1 = __float_as_int(vi.y * LOG2E);
  const int i2 = __float_as_int(vi.z * LOG2E);
  const int i3 = __float_as_int(vi.w * LOG2E);

  float accs = 0.f;
  #pragma unroll 4
  for (int ii = 0; ii < 16; ++ii){
    const int sl = ii * 4;
    float p0 = fabsf(oj[0]  - __int_as_float(__builtin_amdgcn_readlane(i0, sl)))
             + fabsf(oj[1]  - __int_as_float(__builtin_amdgcn_readlane(i1, sl)))
             + fabsf(oj[2]  - __int_as_float(__builtin_amdgcn_readlane(i2, sl)))
             + fabsf(oj[3]  - __int_as_float(__builtin_amdgcn_readlane(i3, sl)));
    float p1 = fabsf(oj[4]  - __int_as_float(__builtin_amdgcn_readlane(i0, sl + 1)))
             + fabsf(oj[5]  - __int_as_float(__builtin_amdgcn_readlane(i1, sl + 1)))
             + fabsf(oj[6]  - __int_as_float(__builtin_amdgcn_readlane(i2, sl + 1)))
             + fabsf(oj[7]  - __int_as_float(__builtin_amdgcn_readlane(i3, sl + 1)));
    float p2 = fabsf(oj[8]  - __int_as_float(__builtin_amdgcn_readlane(i0, sl + 2)))
             + fabsf(oj[9]  - __int_as_float(__builtin_amdgcn_readlane(i1, sl + 2)))
             + fabsf(oj[10] - __int_as_float(__builtin_amdgcn_readlane(i2, sl + 2)))
             + fabsf(oj[11] - __int_as_float(__builtin_amdgcn_readlane(i3, sl + 2)));
    float p3 = fabsf(oj[12] - __int_as_float(__builtin_amdgcn_readlane(i0, sl + 3)))
             + fabsf(oj[13] - __int_as_float(__builtin_amdgcn_readlane(i1, sl + 3)))
             + fabsf(oj[14] - __int_as_float(__builtin_amdgcn_readlane(i2, sl + 3)))
             + fabsf(oj[15] - __int_as_float(__builtin_amdgcn_readlane(i3, sl + 3)));
    accs += exp2f(-((p0 + p1) + (p2 + p3)));
  }
  red[w][lane] = accs;
  __syncthreads();
  if (w == 0){
    float tot = 0.f;
    #pragma unroll
    for (int ww = 0; ww < 16; ++ww) tot += red[ww][lane];
    out[(size_t)j * 64 + b] = tot + bias[b];
  }
}

extern "C" void kernel_launch(void* const* d_in, const int* in_sizes, int n_in,
                              void* d_out, int out_size, void* d_ws, size_t ws_size,
                              hipStream_t stream){
  const float* x    = (const float*)d_in[0];   // [256][1024]
  const float* W    = (const float*)d_in[1];   // [1024][1024] k-major
  const float* bias = (const float*)d_in[2];   // [64]
  float* out = (float*)d_out;                  // [256][64]
  float* P   = (float*)d_ws;                   // 8 MB: partials [8][256][1024]

  k_gemm_ks<<<dim3(4, 16, 8), 256, 0, stream>>>(x, W, P);
  k_pair<<<256, 1024, 0, stream>>>(P, bias, out);
}